// Round 1
// baseline (838.458 us; speedup 1.0000x reference)
//
#include <hip/hip_runtime.h>

#define DM 256
#define NOUT 768
#define JOINTS 22
#define MROWS 88            // 4 frames per block (88 % 22 == 0)
#define QSTR 40             // Q row stride in shorts (16B-aligned, bank-spread)
#define NBLK 1024           // 90112 / 88

typedef __attribute__((ext_vector_type(8))) short bf16x8;
typedef __attribute__((ext_vector_type(4))) float f32x4;

__device__ __forceinline__ float b2f(unsigned short u) {
    union { unsigned int i; float f; } x; x.i = ((unsigned int)u) << 16; return x.f;
}
__device__ __forceinline__ float blo(unsigned int w) {
    union { unsigned int i; float f; } x; x.i = w << 16; return x.f;
}
__device__ __forceinline__ float bhi(unsigned int w) {
    union { unsigned int i; float f; } x; x.i = w & 0xFFFF0000u; return x.f;
}
__device__ __forceinline__ unsigned short f2b(float f) {
    union { float f; unsigned int u; } x; x.f = f;
    unsigned int r = x.u + 0x7FFFu + ((x.u >> 16) & 1u);
    return (unsigned short)(r >> 16);
}

// ws layout
#define OFF_PEWB 0
#define OFF_WCAN (JOINTS * NOUT * 4)                 // 67584

// ---------------- convert W (fp32 -> bf16), 3 matrices ----------------
__global__ __launch_bounds__(256) void wconv_kernel(const float* __restrict__ w0,
                                                    const float* __restrict__ w1,
                                                    const float* __restrict__ w2,
                                                    unsigned short* __restrict__ wcan)
{
    const float* w = (blockIdx.y == 0) ? w0 : (blockIdx.y == 1 ? w1 : w2);
    int i = (blockIdx.x * 256 + threadIdx.x) * 8;
    const float* s = w + i;
    union { uint4 v; float f[4]; } a, b;
    a.v = *(const uint4*)(s);
    b.v = *(const uint4*)(s + 4);
    union { uint4 v; unsigned short u[8]; } o;
    #pragma unroll
    for (int k = 0; k < 4; ++k) { o.u[k] = f2b(a.f[k]); o.u[4 + k] = f2b(b.f[k]); }
    *(uint4*)(wcan + blockIdx.y * (DM * DM) + i) = o.v;
}

// ---------------- PEWB[j,e] = bias[e] + sum_d pe[j,d] * W[e,d]  (fp32) ----------------
__global__ __launch_bounds__(256) void pewb_kernel(const float* __restrict__ wq,
                                                   const float* __restrict__ wk,
                                                   const float* __restrict__ wv,
                                                   const float* __restrict__ bq,
                                                   const float* __restrict__ bk,
                                                   const float* __restrict__ bv,
                                                   float* __restrict__ pewb)
{
    __shared__ float pe_s[DM];
    const int j   = blockIdx.x / 3;
    const int mat = blockIdx.x % 3;
    const int t = threadIdx.x;
    {
        int i = t >> 1;
        float div = __expf((float)(2 * i) * (-9.210340371976184f / 256.0f)); // -ln(10000)/256
        float ang = (float)j * div;
        pe_s[t] = (t & 1) ? cosf(ang) : sinf(ang);
    }
    __syncthreads();
    const float* w  = (mat == 0) ? wq : (mat == 1 ? wk : wv);
    const float* bb = (mat == 0) ? bq : (mat == 1 ? bk : bv);
    float acc = bb[t];
    const float* wr = w + (size_t)t * DM;
    #pragma unroll 8
    for (int d = 0; d < DM; ++d) acc += pe_s[d] * wr[d];
    pewb[j * NOUT + mat * DM + t] = acc;
}

// ---------------- fused QKV-GEMM + block-diagonal attention ----------------
// One block = 88 tokens (4 frames) of one batch row. Loops 4x over head pairs:
//   MFMA GEMM (96x192x256, W from L2) -> epilogue (+PEWB) -> LDS Q/K/V -> VALU attn -> out.
__global__ __launch_bounds__(512, 4) void fused_kernel(const float* __restrict__ x,
                                                       const unsigned short* __restrict__ wcan,
                                                       const float* __restrict__ pewb,
                                                       float* __restrict__ out)
{
    __shared__ __align__(16) unsigned short xs[MROWS * 256];        // 45056 B, chunk-swizzled
    __shared__ __align__(16) unsigned short q_s[2 * MROWS * QSTR];  // 14080 B
    __shared__ __align__(16) unsigned short k_s[2 * MROWS * 32];    // 11264 B
    __shared__ __align__(16) unsigned short v_s[2 * MROWS * 32];    // 11264 B  (total 81664)

    const int t    = threadIdx.x;
    const int tok0 = blockIdx.x * MROWS;   // 88*bid == (bid>>1)*176 + (bid&1)*88

    // ---- stage x tile fp32 -> bf16, swizzled (chunk c at (c&24)|((c&7)^(row&7))) ----
    for (int i = t; i < MROWS * 32; i += 512) {
        int row = i >> 5, c = i & 31;
        const float* src = x + (size_t)(tok0 + row) * DM + c * 8;
        union { uint4 v; float f[4]; } a, b;
        a.v = *(const uint4*)(src);
        b.v = *(const uint4*)(src + 4);
        union { uint4 v; unsigned short u[8]; } o;
        #pragma unroll
        for (int k = 0; k < 4; ++k) { o.u[k] = f2b(a.f[k]); o.u[4 + k] = f2b(b.f[k]); }
        int cs = (c & 24) | ((c & 7) ^ (row & 7));
        *(uint4*)(&xs[row * 256 + cs * 8]) = o.v;
    }
    __syncthreads();

    const int lane = t & 63;
    const int wave = t >> 6;
    const int wm   = (wave & 1) * 48;      // M wave-group: rows [wm, wm+48)
    const int wn   = (wave >> 1) * 48;     // N wave-group: cols [wn, wn+48) of 192
    const int lrow = lane & 15;
    const int quad = lane >> 4;

    // A-fragment row indices (M padded 88->96: clamp, results masked at store)
    int abase[3], axor[3];
    #pragma unroll
    for (int mi = 0; mi < 3; ++mi) {
        int ar = wm + mi * 16 + lrow;
        if (ar > MROWS - 1) ar = MROWS - 1;
        abase[mi] = ar * 256;
        axor[mi]  = ar & 7;
    }

    for (int it = 0; it < 4; ++it) {
        const int h0 = it * 2;

        // B row pointers: col n of this iter -> W row. n: mat=n>>6, hl=(n>>5)&1, d=n&31
        const unsigned short* bp[3];
        #pragma unroll
        for (int ni = 0; ni < 3; ++ni) {
            int n   = wn + ni * 16 + lrow;
            int mat = n >> 6;
            int e   = (h0 + ((n >> 5) & 1)) * 32 + (n & 31);
            bp[ni] = wcan + mat * (DM * DM) + (size_t)e * DM + quad * 8;
        }

        f32x4 acc[3][3];
        #pragma unroll
        for (int mi = 0; mi < 3; ++mi)
            #pragma unroll
            for (int ni = 0; ni < 3; ++ni)
                acc[mi][ni] = (f32x4){0.f, 0.f, 0.f, 0.f};

        #pragma unroll
        for (int kk = 0; kk < DM; kk += 32) {
            bf16x8 a[3], b[3];
            #pragma unroll
            for (int mi = 0; mi < 3; ++mi) {
                int c  = (kk >> 3) + quad;
                int cs = (c & 24) | ((c & 7) ^ axor[mi]);
                a[mi] = *(const bf16x8*)(&xs[abase[mi] + cs * 8]);
            }
            #pragma unroll
            for (int ni = 0; ni < 3; ++ni)
                b[ni] = *(const bf16x8*)(bp[ni] + kk);
            #pragma unroll
            for (int mi = 0; mi < 3; ++mi)
                #pragma unroll
                for (int ni = 0; ni < 3; ++ni)
                    acc[mi][ni] = __builtin_amdgcn_mfma_f32_16x16x32_bf16(
                        a[mi], b[ni], acc[mi][ni], 0, 0, 0);
        }

        __syncthreads();   // previous iter's attn readers are done with q/k/v LDS

        // ---- epilogue: + PEWB[joint], store bf16 into Q/K/V LDS ----
        #pragma unroll
        for (int ni = 0; ni < 3; ++ni) {
            int n   = wn + ni * 16 + lrow;
            int mat = n >> 6;            // wave-uniform (16-aligned slices)
            int hl  = (n >> 5) & 1;
            int d   = n & 31;
            int pcol = mat * 256 + (h0 + hl) * 32 + d;
            unsigned short* dst;
            int str;
            if (mat == 0)      { dst = &q_s[(hl * MROWS) * QSTR + d]; str = QSTR; }
            else if (mat == 1) { dst = &k_s[(hl * MROWS) * 32 + d];   str = 32; }
            else               { dst = &v_s[(hl * MROWS) * 32 + d];   str = 32; }
            #pragma unroll
            for (int mi = 0; mi < 3; ++mi) {
                int rbase = wm + mi * 16 + quad * 4;   // C row = quad*4 + reg
                if (rbase < MROWS) {
                    #pragma unroll
                    for (int rg = 0; rg < 4; ++rg) {
                        int r = rbase + rg;
                        int joint = r % 22;            // tok0 % 22 == 0
                        float val = acc[mi][ni][rg] + pewb[joint * NOUT + pcol];
                        dst[r * str] = f2b(val);
                    }
                }
            }
        }
        __syncthreads();

        // ---- attention: 2 threads per (row, local head); d split 16+16 ----
        if (t < 2 * 2 * MROWS) {          // 352 active
            const int rid = t >> 1;
            const int dh  = (t & 1) << 4;
            const int hl  = (rid >= MROWS) ? 1 : 0;
            const int r   = rid - hl * MROWS;
            const int fr  = r / 22;

            float q[16];
            {
                const unsigned short* qp = &q_s[(hl * MROWS + r) * QSTR + dh];
                union { uint4 v; unsigned int w[4]; } a0, a1;
                a0.v = *(const uint4*)(qp);
                a1.v = *(const uint4*)(qp + 8);
                #pragma unroll
                for (int i = 0; i < 4; ++i) {
                    q[2 * i]     = blo(a0.w[i]) * 0.17677669529663688f;  // 1/sqrt(32)
                    q[2 * i + 1] = bhi(a0.w[i]) * 0.17677669529663688f;
                    q[8 + 2 * i]     = blo(a1.w[i]) * 0.17677669529663688f;
                    q[8 + 2 * i + 1] = bhi(a1.w[i]) * 0.17677669529663688f;
                }
            }

            const unsigned short* kp = &k_s[(hl * MROWS + fr * 22) * 32 + dh];
            float sc[22];
            float mx = -3.0e38f;
            #pragma unroll
            for (int j = 0; j < 22; ++j) {
                union { uint4 v; unsigned int w[4]; } a0, a1;
                a0.v = *(const uint4*)(kp + j * 32);
                a1.v = *(const uint4*)(kp + j * 32 + 8);
                float s = 0.f;
                #pragma unroll
                for (int i = 0; i < 4; ++i) {
                    s += q[2 * i]     * blo(a0.w[i]);
                    s += q[2 * i + 1] * bhi(a0.w[i]);
                    s += q[8 + 2 * i]     * blo(a1.w[i]);
                    s += q[8 + 2 * i + 1] * bhi(a1.w[i]);
                }
                s += __shfl_xor(s, 1);    // combine the two d-halves
                sc[j] = s;
                mx = fmaxf(mx, s);
            }
            float sum = 0.f;
            #pragma unroll
            for (int j = 0; j < 22; ++j) { sc[j] = __expf(sc[j] - mx); sum += sc[j]; }
            float inv = 1.f / sum;

            float o[16];
            #pragma unroll
            for (int d = 0; d < 16; ++d) o[d] = 0.f;
            const unsigned short* vp = &v_s[(hl * MROWS + fr * 22) * 32 + dh];
            #pragma unroll
            for (int j = 0; j < 22; ++j) {
                float p = sc[j] * inv;
                union { uint4 v; unsigned int w[4]; } a0, a1;
                a0.v = *(const uint4*)(vp + j * 32);
                a1.v = *(const uint4*)(vp + j * 32 + 8);
                #pragma unroll
                for (int i = 0; i < 4; ++i) {
                    o[2 * i]     += p * blo(a0.w[i]);
                    o[2 * i + 1] += p * bhi(a0.w[i]);
                    o[8 + 2 * i]     += p * blo(a1.w[i]);
                    o[8 + 2 * i + 1] += p * bhi(a1.w[i]);
                }
            }

            float* op = out + (size_t)(tok0 + r) * DM + ((h0 + hl) << 5) + dh;
            *(float4*)(op)      = make_float4(o[0],  o[1],  o[2],  o[3]);
            *(float4*)(op + 4)  = make_float4(o[4],  o[5],  o[6],  o[7]);
            *(float4*)(op + 8)  = make_float4(o[8],  o[9],  o[10], o[11]);
            *(float4*)(op + 12) = make_float4(o[12], o[13], o[14], o[15]);
        }
        // no barrier here: next iter's MFMA doesn't touch q/k/v; its pre-epilogue
        // barrier protects the buffers. Waves 6-7 (no attn rows) run ahead into MFMA.
    }
}

extern "C" void kernel_launch(void* const* d_in, const int* in_sizes, int n_in,
                              void* d_out, int out_size, void* d_ws, size_t ws_size,
                              hipStream_t stream) {
    const float* x  = (const float*)d_in[0];
    const float* wq = (const float*)d_in[1];
    const float* bq = (const float*)d_in[2];
    const float* wk = (const float*)d_in[3];
    const float* bk = (const float*)d_in[4];
    const float* wv = (const float*)d_in[5];
    const float* bv = (const float*)d_in[6];

    char* ws = (char*)d_ws;
    float*          pewb = (float*)(ws + OFF_PEWB);
    unsigned short* wcan = (unsigned short*)(ws + OFF_WCAN);

    wconv_kernel<<<dim3(32, 3), dim3(256), 0, stream>>>(wq, wk, wv, wcan);
    pewb_kernel<<<dim3(66), dim3(256), 0, stream>>>(wq, wk, wv, bq, bk, bv, pewb);
    fused_kernel<<<dim3(NBLK), dim3(512), 0, stream>>>(x, wcan, pewb, (float*)d_out);
}

// Round 2
// 835.571 us; speedup vs baseline: 1.0035x; 1.0035x over previous
//
#include <hip/hip_runtime.h>

#define DM 256
#define NOUT 768
#define JOINTS 22
#define MROWS 88            // 4 frames per block (88 % 22 == 0)
#define QSTR 40             // Q row stride in shorts (16B-aligned, bank-spread)
#define NBLK 1024           // 90112 / 88

typedef __attribute__((ext_vector_type(8))) short bf16x8;
typedef __attribute__((ext_vector_type(4))) float f32x4;

__device__ __forceinline__ float b2f(unsigned short u) {
    union { unsigned int i; float f; } x; x.i = ((unsigned int)u) << 16; return x.f;
}
__device__ __forceinline__ float blo(unsigned int w) {
    union { unsigned int i; float f; } x; x.i = w << 16; return x.f;
}
__device__ __forceinline__ float bhi(unsigned int w) {
    union { unsigned int i; float f; } x; x.i = w & 0xFFFF0000u; return x.f;
}
__device__ __forceinline__ unsigned short f2b(float f) {
    union { float f; unsigned int u; } x; x.f = f;
    unsigned int r = x.u + 0x7FFFu + ((x.u >> 16) & 1u);
    return (unsigned short)(r >> 16);
}

// ws layout
#define OFF_PEWB 0
#define OFF_WCAN (JOINTS * NOUT * 4)                 // 67584

// ---------------- convert W (fp32 -> bf16), 3 matrices ----------------
__global__ __launch_bounds__(256) void wconv_kernel(const float* __restrict__ w0,
                                                    const float* __restrict__ w1,
                                                    const float* __restrict__ w2,
                                                    unsigned short* __restrict__ wcan)
{
    const float* w = (blockIdx.y == 0) ? w0 : (blockIdx.y == 1 ? w1 : w2);
    int i = (blockIdx.x * 256 + threadIdx.x) * 8;
    const float* s = w + i;
    union { uint4 v; float f[4]; } a, b;
    a.v = *(const uint4*)(s);
    b.v = *(const uint4*)(s + 4);
    union { uint4 v; unsigned short u[8]; } o;
    #pragma unroll
    for (int k = 0; k < 4; ++k) { o.u[k] = f2b(a.f[k]); o.u[4 + k] = f2b(b.f[k]); }
    *(uint4*)(wcan + blockIdx.y * (DM * DM) + i) = o.v;
}

// ---------------- PEWB[j,e] = bias[e] + sum_d pe[j,d] * W[e,d]  (fp32) ----------------
__global__ __launch_bounds__(256) void pewb_kernel(const float* __restrict__ wq,
                                                   const float* __restrict__ wk,
                                                   const float* __restrict__ wv,
                                                   const float* __restrict__ bq,
                                                   const float* __restrict__ bk,
                                                   const float* __restrict__ bv,
                                                   float* __restrict__ pewb)
{
    __shared__ float pe_s[DM];
    const int j   = blockIdx.x / 3;
    const int mat = blockIdx.x % 3;
    const int t = threadIdx.x;
    {
        int i = t >> 1;
        float div = __expf((float)(2 * i) * (-9.210340371976184f / 256.0f)); // -ln(10000)/256
        float ang = (float)j * div;
        pe_s[t] = (t & 1) ? cosf(ang) : sinf(ang);
    }
    __syncthreads();
    const float* w  = (mat == 0) ? wq : (mat == 1 ? wk : wv);
    const float* bb = (mat == 0) ? bq : (mat == 1 ? bk : bv);
    float acc = bb[t];
    const float* wr = w + (size_t)t * DM;
    #pragma unroll 8
    for (int d = 0; d < DM; ++d) acc += pe_s[d] * wr[d];
    pewb[j * NOUT + mat * DM + t] = acc;
}

// ---------------- fused QKV-GEMM + block-diagonal attention ----------------
// One block = 88 tokens (4 frames) of one batch row. Loops 4x over head pairs:
//   MFMA GEMM (96x192x256, W from L2) -> epilogue (+PEWB) -> LDS Q/K/V -> VALU attn -> out.
// Register discipline: it-loop unroll 1 (phases never merge), K-loop unroll 1 with
// manual 2-deep B double-buffer (max 6 B-frags = 24 VGPR in flight).
__global__ __launch_bounds__(512, 4) void fused_kernel(const float* __restrict__ x,
                                                       const unsigned short* __restrict__ wcan,
                                                       const float* __restrict__ pewb,
                                                       float* __restrict__ out)
{
    __shared__ __align__(16) unsigned short xs[MROWS * 256];        // 45056 B, chunk-swizzled
    __shared__ __align__(16) unsigned short q_s[2 * MROWS * QSTR];  // 14080 B
    __shared__ __align__(16) unsigned short k_s[2 * MROWS * 32];    // 11264 B
    __shared__ __align__(16) unsigned short v_s[2 * MROWS * 32];    // 11264 B  (total 81664)

    const int t    = threadIdx.x;
    const int tok0 = blockIdx.x * MROWS;

    // ---- stage x tile fp32 -> bf16, swizzled (chunk c at (c&24)|((c&7)^(row&7))) ----
    for (int i = t; i < MROWS * 32; i += 512) {
        int row = i >> 5, c = i & 31;
        const float* src = x + (size_t)(tok0 + row) * DM + c * 8;
        union { uint4 v; float f[4]; } a, b;
        a.v = *(const uint4*)(src);
        b.v = *(const uint4*)(src + 4);
        union { uint4 v; unsigned short u[8]; } o;
        #pragma unroll
        for (int k = 0; k < 4; ++k) { o.u[k] = f2b(a.f[k]); o.u[4 + k] = f2b(b.f[k]); }
        int cs = (c & 24) | ((c & 7) ^ (row & 7));
        *(uint4*)(&xs[row * 256 + cs * 8]) = o.v;
    }
    __syncthreads();

    const int lane = t & 63;
    const int wave = t >> 6;
    const int wm   = (wave & 1) * 48;      // M wave-group: rows [wm, wm+48)
    const int wn   = (wave >> 1) * 48;     // N wave-group: cols [wn, wn+48) of 192
    const int lrow = lane & 15;
    const int quad = lane >> 4;

    // A-fragment row indices (M padded 88->96: clamp, results masked at store)
    int abase[3], axor[3];
    #pragma unroll
    for (int mi = 0; mi < 3; ++mi) {
        int ar = wm + mi * 16 + lrow;
        if (ar > MROWS - 1) ar = MROWS - 1;
        abase[mi] = ar * 256;
        axor[mi]  = ar & 7;
    }

    #pragma unroll 1
    for (int it = 0; it < 4; ++it) {
        const int h0 = it * 2;

        // B row pointers: col n of this iter -> W row. n: mat=n>>6, hl=(n>>5)&1, d=n&31
        const unsigned short* bp[3];
        #pragma unroll
        for (int ni = 0; ni < 3; ++ni) {
            int n   = wn + ni * 16 + lrow;
            int mat = n >> 6;
            int e   = (h0 + ((n >> 5) & 1)) * 32 + (n & 31);
            bp[ni] = wcan + mat * (DM * DM) + (size_t)e * DM + quad * 8;
        }

        f32x4 acc[3][3];
        #pragma unroll
        for (int mi = 0; mi < 3; ++mi)
            #pragma unroll
            for (int ni = 0; ni < 3; ++ni)
                acc[mi][ni] = (f32x4){0.f, 0.f, 0.f, 0.f};

        auto kstep = [&](int kk, bf16x8* breg) {
            bf16x8 a[3];
            int c = (kk >> 3) + quad;
            #pragma unroll
            for (int mi = 0; mi < 3; ++mi) {
                int cs = (c & 24) | ((c & 7) ^ axor[mi]);
                a[mi] = *(const bf16x8*)(&xs[abase[mi] + cs * 8]);
            }
            #pragma unroll
            for (int mi = 0; mi < 3; ++mi)
                #pragma unroll
                for (int ni = 0; ni < 3; ++ni)
                    acc[mi][ni] = __builtin_amdgcn_mfma_f32_16x16x32_bf16(
                        a[mi], breg[ni], acc[mi][ni], 0, 0, 0);
        };

        bf16x8 bA[3], bB[3];
        #pragma unroll
        for (int ni = 0; ni < 3; ++ni) bA[ni] = *(const bf16x8*)(bp[ni]);
        #pragma unroll 1
        for (int kk = 0; kk < 192; kk += 64) {
            #pragma unroll
            for (int ni = 0; ni < 3; ++ni) bB[ni] = *(const bf16x8*)(bp[ni] + kk + 32);
            kstep(kk, bA);
            #pragma unroll
            for (int ni = 0; ni < 3; ++ni) bA[ni] = *(const bf16x8*)(bp[ni] + kk + 64);
            kstep(kk + 32, bB);
        }
        #pragma unroll
        for (int ni = 0; ni < 3; ++ni) bB[ni] = *(const bf16x8*)(bp[ni] + 224);
        kstep(192, bA);
        kstep(224, bB);

        __syncthreads();   // previous iter's attn readers are done with q/k/v LDS

        // ---- epilogue: + PEWB[joint], store bf16 into Q/K/V LDS ----
        #pragma unroll
        for (int ni = 0; ni < 3; ++ni) {
            int n   = wn + ni * 16 + lrow;
            int mat = n >> 6;            // wave-uniform (16-aligned slices)
            int hl  = (n >> 5) & 1;
            int d   = n & 31;
            int pcol = mat * 256 + (h0 + hl) * 32 + d;
            unsigned short* dst;
            int str;
            if (mat == 0)      { dst = &q_s[(hl * MROWS) * QSTR + d]; str = QSTR; }
            else if (mat == 1) { dst = &k_s[(hl * MROWS) * 32 + d];   str = 32; }
            else               { dst = &v_s[(hl * MROWS) * 32 + d];   str = 32; }
            #pragma unroll
            for (int mi = 0; mi < 3; ++mi) {
                int rbase = wm + mi * 16 + quad * 4;   // C row = quad*4 + reg
                if (rbase < MROWS) {
                    #pragma unroll
                    for (int rg = 0; rg < 4; ++rg) {
                        int r = rbase + rg;
                        int joint = r % 22;            // tok0 % 22 == 0
                        float val = acc[mi][ni][rg] + pewb[joint * NOUT + pcol];
                        dst[r * str] = f2b(val);
                    }
                }
            }
        }
        __syncthreads();

        // ---- attention: 2 threads per (row, local head); d split 16+16 ----
        if (t < 2 * 2 * MROWS) {          // 352 active
            const int rid = t >> 1;
            const int dh  = (t & 1) << 4;
            const int hl  = (rid >= MROWS) ? 1 : 0;
            const int r   = rid - hl * MROWS;
            const int fr  = r / 22;

            float q[16];
            {
                const unsigned short* qp = &q_s[(hl * MROWS + r) * QSTR + dh];
                union { uint4 v; unsigned int w[4]; } a0, a1;
                a0.v = *(const uint4*)(qp);
                a1.v = *(const uint4*)(qp + 8);
                #pragma unroll
                for (int i = 0; i < 4; ++i) {
                    q[2 * i]     = blo(a0.w[i]) * 0.17677669529663688f;  // 1/sqrt(32)
                    q[2 * i + 1] = bhi(a0.w[i]) * 0.17677669529663688f;
                    q[8 + 2 * i]     = blo(a1.w[i]) * 0.17677669529663688f;
                    q[8 + 2 * i + 1] = bhi(a1.w[i]) * 0.17677669529663688f;
                }
            }

            const unsigned short* kp = &k_s[(hl * MROWS + fr * 22) * 32 + dh];
            float sc[22];
            float mx = -3.0e38f;
            #pragma unroll
            for (int j = 0; j < 22; ++j) {
                union { uint4 v; unsigned int w[4]; } a0, a1;
                a0.v = *(const uint4*)(kp + j * 32);
                a1.v = *(const uint4*)(kp + j * 32 + 8);
                float s = 0.f;
                #pragma unroll
                for (int i = 0; i < 4; ++i) {
                    s += q[2 * i]     * blo(a0.w[i]);
                    s += q[2 * i + 1] * bhi(a0.w[i]);
                    s += q[8 + 2 * i]     * blo(a1.w[i]);
                    s += q[8 + 2 * i + 1] * bhi(a1.w[i]);
                }
                s += __shfl_xor(s, 1);    // combine the two d-halves
                sc[j] = s;
                mx = fmaxf(mx, s);
            }
            float sum = 0.f;
            #pragma unroll
            for (int j = 0; j < 22; ++j) { sc[j] = __expf(sc[j] - mx); sum += sc[j]; }
            float inv = 1.f / sum;

            float o[16];
            #pragma unroll
            for (int d = 0; d < 16; ++d) o[d] = 0.f;
            const unsigned short* vp = &v_s[(hl * MROWS + fr * 22) * 32 + dh];
            #pragma unroll
            for (int j = 0; j < 22; ++j) {
                float p = sc[j] * inv;
                union { uint4 v; unsigned int w[4]; } a0, a1;
                a0.v = *(const uint4*)(vp + j * 32);
                a1.v = *(const uint4*)(vp + j * 32 + 8);
                #pragma unroll
                for (int i = 0; i < 4; ++i) {
                    o[2 * i]     += p * blo(a0.w[i]);
                    o[2 * i + 1] += p * bhi(a0.w[i]);
                    o[8 + 2 * i]     += p * blo(a1.w[i]);
                    o[8 + 2 * i + 1] += p * bhi(a1.w[i]);
                }
            }

            float* op = out + (size_t)(tok0 + r) * DM + ((h0 + hl) << 5) + dh;
            *(float4*)(op)      = make_float4(o[0],  o[1],  o[2],  o[3]);
            *(float4*)(op + 4)  = make_float4(o[4],  o[5],  o[6],  o[7]);
            *(float4*)(op + 8)  = make_float4(o[8],  o[9],  o[10], o[11]);
            *(float4*)(op + 12) = make_float4(o[12], o[13], o[14], o[15]);
        }
        // no barrier here: next iter's MFMA doesn't touch q/k/v; its pre-epilogue
        // barrier protects the buffers. Waves 6-7 (no attn rows) run ahead into MFMA.
    }
}

extern "C" void kernel_launch(void* const* d_in, const int* in_sizes, int n_in,
                              void* d_out, int out_size, void* d_ws, size_t ws_size,
                              hipStream_t stream) {
    const float* x  = (const float*)d_in[0];
    const float* wq = (const float*)d_in[1];
    const float* bq = (const float*)d_in[2];
    const float* wk = (const float*)d_in[3];
    const float* bk = (const float*)d_in[4];
    const float* wv = (const float*)d_in[5];
    const float* bv = (const float*)d_in[6];

    char* ws = (char*)d_ws;
    float*          pewb = (float*)(ws + OFF_PEWB);
    unsigned short* wcan = (unsigned short*)(ws + OFF_WCAN);

    wconv_kernel<<<dim3(32, 3), dim3(256), 0, stream>>>(wq, wk, wv, wcan);
    pewb_kernel<<<dim3(66), dim3(256), 0, stream>>>(wq, wk, wv, bq, bk, bv, pewb);
    fused_kernel<<<dim3(NBLK), dim3(512), 0, stream>>>(x, wcan, pewb, (float*)d_out);
}

// Round 3
// 383.523 us; speedup vs baseline: 2.1862x; 2.1787x over previous
//
#include <hip/hip_runtime.h>

#define DM 256
#define NOUT 768
#define JOINTS 22
#define MROWS 88            // 4 frames per block (88 % 22 == 0)
#define QSTR 40             // Q row stride in shorts (16B-aligned, bank-spread)
#define NBLK 1024           // 90112 / 88

typedef __attribute__((ext_vector_type(8))) short bf16x8;
typedef __attribute__((ext_vector_type(4))) float f32x4;

__device__ __forceinline__ float b2f(unsigned short u) {
    union { unsigned int i; float f; } x; x.i = ((unsigned int)u) << 16; return x.f;
}
__device__ __forceinline__ float blo(unsigned int w) {
    union { unsigned int i; float f; } x; x.i = w << 16; return x.f;
}
__device__ __forceinline__ float bhi(unsigned int w) {
    union { unsigned int i; float f; } x; x.i = w & 0xFFFF0000u; return x.f;
}
__device__ __forceinline__ unsigned short f2b(float f) {
    union { float f; unsigned int u; } x; x.f = f;
    unsigned int r = x.u + 0x7FFFu + ((x.u >> 16) & 1u);
    return (unsigned short)(r >> 16);
}

// ws layout
#define OFF_PEWB 0
#define OFF_WCAN (JOINTS * NOUT * 4)                 // 67584

// ---------------- convert W (fp32 -> bf16), 3 matrices ----------------
__global__ __launch_bounds__(256) void wconv_kernel(const float* __restrict__ w0,
                                                    const float* __restrict__ w1,
                                                    const float* __restrict__ w2,
                                                    unsigned short* __restrict__ wcan)
{
    const float* w = (blockIdx.y == 0) ? w0 : (blockIdx.y == 1 ? w1 : w2);
    int i = (blockIdx.x * 256 + threadIdx.x) * 8;
    const float* s = w + i;
    union { uint4 v; float f[4]; } a, b;
    a.v = *(const uint4*)(s);
    b.v = *(const uint4*)(s + 4);
    union { uint4 v; unsigned short u[8]; } o;
    #pragma unroll
    for (int k = 0; k < 4; ++k) { o.u[k] = f2b(a.f[k]); o.u[4 + k] = f2b(b.f[k]); }
    *(uint4*)(wcan + blockIdx.y * (DM * DM) + i) = o.v;
}

// ---------------- PEWB[j,e] = bias[e] + sum_d pe[j,d] * W[e,d]  (fp32) ----------------
__global__ __launch_bounds__(256) void pewb_kernel(const float* __restrict__ wq,
                                                   const float* __restrict__ wk,
                                                   const float* __restrict__ wv,
                                                   const float* __restrict__ bq,
                                                   const float* __restrict__ bk,
                                                   const float* __restrict__ bv,
                                                   float* __restrict__ pewb)
{
    __shared__ float pe_s[DM];
    const int j   = blockIdx.x / 3;
    const int mat = blockIdx.x % 3;
    const int t = threadIdx.x;
    {
        int i = t >> 1;
        float div = __expf((float)(2 * i) * (-9.210340371976184f / 256.0f)); // -ln(10000)/256
        float ang = (float)j * div;
        pe_s[t] = (t & 1) ? cosf(ang) : sinf(ang);
    }
    __syncthreads();
    const float* w  = (mat == 0) ? wq : (mat == 1 ? wk : wv);
    const float* bb = (mat == 0) ? bq : (mat == 1 ? bk : bv);
    float acc = bb[t];
    const float* wr = w + (size_t)t * DM;
    #pragma unroll 8
    for (int d = 0; d < DM; ++d) acc += pe_s[d] * wr[d];
    pewb[j * NOUT + mat * DM + t] = acc;
}

// ---------------- fused QKV-GEMM + block-diagonal attention ----------------
// One block = 88 tokens (4 frames) of one batch row. Loops 4x over head pairs:
//   MFMA GEMM (96x192x256, W from L2) -> epilogue (+PEWB) -> LDS Q/K/V -> VALU attn -> out.
// __launch_bounds__(512, 2): LDS (81920 B) caps residency at 2 blocks/CU anyway;
// asking for 4 made the allocator pin VGPRs at 64 -> 2.4 GB of spill traffic.
// With min=2 the cap is 128 VGPR, which fits the ~110-reg peak pressure.
__global__ __launch_bounds__(512, 2) void fused_kernel(const float* __restrict__ x,
                                                       const unsigned short* __restrict__ wcan,
                                                       const float* __restrict__ pewb,
                                                       float* __restrict__ out)
{
    __shared__ __align__(16) unsigned short xs[MROWS * 256];        // 45056 B, chunk-swizzled
    __shared__ __align__(16) unsigned short q_s[2 * MROWS * QSTR];  // 14080 B
    __shared__ __align__(16) unsigned short k_s[2 * MROWS * 32];    // 11264 B
    __shared__ __align__(16) unsigned short v_s[2 * MROWS * 32];    // 11264 B  (total 81664)

    const int t    = threadIdx.x;
    const int tok0 = blockIdx.x * MROWS;

    // ---- stage x tile fp32 -> bf16, swizzled (chunk c at (c&24)|((c&7)^(row&7))) ----
    for (int i = t; i < MROWS * 32; i += 512) {
        int row = i >> 5, c = i & 31;
        const float* src = x + (size_t)(tok0 + row) * DM + c * 8;
        union { uint4 v; float f[4]; } a, b;
        a.v = *(const uint4*)(src);
        b.v = *(const uint4*)(src + 4);
        union { uint4 v; unsigned short u[8]; } o;
        #pragma unroll
        for (int k = 0; k < 4; ++k) { o.u[k] = f2b(a.f[k]); o.u[4 + k] = f2b(b.f[k]); }
        int cs = (c & 24) | ((c & 7) ^ (row & 7));
        *(uint4*)(&xs[row * 256 + cs * 8]) = o.v;
    }
    __syncthreads();

    const int lane = t & 63;
    const int wave = t >> 6;
    const int wm   = (wave & 1) * 48;      // M wave-group: rows [wm, wm+48)
    const int wn   = (wave >> 1) * 48;     // N wave-group: cols [wn, wn+48) of 192
    const int lrow = lane & 15;
    const int quad = lane >> 4;

    // A-fragment row indices (M padded 88->96: clamp, results masked at store)
    int abase[3], axor[3];
    #pragma unroll
    for (int mi = 0; mi < 3; ++mi) {
        int ar = wm + mi * 16 + lrow;
        if (ar > MROWS - 1) ar = MROWS - 1;
        abase[mi] = ar * 256;
        axor[mi]  = ar & 7;
    }

    #pragma unroll 1
    for (int it = 0; it < 4; ++it) {
        const int h0 = it * 2;

        // B row pointers: col n of this iter -> W row. n: mat=n>>6, hl=(n>>5)&1, d=n&31
        const unsigned short* bp[3];
        #pragma unroll
        for (int ni = 0; ni < 3; ++ni) {
            int n   = wn + ni * 16 + lrow;
            int mat = n >> 6;
            int e   = (h0 + ((n >> 5) & 1)) * 32 + (n & 31);
            bp[ni] = wcan + mat * (DM * DM) + (size_t)e * DM + quad * 8;
        }

        f32x4 acc[3][3];
        #pragma unroll
        for (int mi = 0; mi < 3; ++mi)
            #pragma unroll
            for (int ni = 0; ni < 3; ++ni)
                acc[mi][ni] = (f32x4){0.f, 0.f, 0.f, 0.f};

        auto kstep = [&](int kk, bf16x8* breg) {
            bf16x8 a[3];
            int c = (kk >> 3) + quad;
            #pragma unroll
            for (int mi = 0; mi < 3; ++mi) {
                int cs = (c & 24) | ((c & 7) ^ axor[mi]);
                a[mi] = *(const bf16x8*)(&xs[abase[mi] + cs * 8]);
            }
            #pragma unroll
            for (int mi = 0; mi < 3; ++mi)
                #pragma unroll
                for (int ni = 0; ni < 3; ++ni)
                    acc[mi][ni] = __builtin_amdgcn_mfma_f32_16x16x32_bf16(
                        a[mi], breg[ni], acc[mi][ni], 0, 0, 0);
        };

        bf16x8 bA[3], bB[3];
        #pragma unroll
        for (int ni = 0; ni < 3; ++ni) bA[ni] = *(const bf16x8*)(bp[ni]);
        #pragma unroll 1
        for (int kk = 0; kk < 192; kk += 64) {
            #pragma unroll
            for (int ni = 0; ni < 3; ++ni) bB[ni] = *(const bf16x8*)(bp[ni] + kk + 32);
            kstep(kk, bA);
            #pragma unroll
            for (int ni = 0; ni < 3; ++ni) bA[ni] = *(const bf16x8*)(bp[ni] + kk + 64);
            kstep(kk + 32, bB);
        }
        #pragma unroll
        for (int ni = 0; ni < 3; ++ni) bB[ni] = *(const bf16x8*)(bp[ni] + 224);
        kstep(192, bA);
        kstep(224, bB);

        __syncthreads();   // previous iter's attn readers are done with q/k/v LDS

        // ---- epilogue: + PEWB[joint], store bf16 into Q/K/V LDS ----
        #pragma unroll
        for (int ni = 0; ni < 3; ++ni) {
            int n   = wn + ni * 16 + lrow;
            int mat = n >> 6;            // wave-uniform (16-aligned slices)
            int hl  = (n >> 5) & 1;
            int d   = n & 31;
            int pcol = mat * 256 + (h0 + hl) * 32 + d;
            unsigned short* dst;
            int str;
            if (mat == 0)      { dst = &q_s[(hl * MROWS) * QSTR + d]; str = QSTR; }
            else if (mat == 1) { dst = &k_s[(hl * MROWS) * 32 + d];   str = 32; }
            else               { dst = &v_s[(hl * MROWS) * 32 + d];   str = 32; }
            #pragma unroll
            for (int mi = 0; mi < 3; ++mi) {
                int rbase = wm + mi * 16 + quad * 4;   // C row = quad*4 + reg
                if (rbase < MROWS) {
                    #pragma unroll
                    for (int rg = 0; rg < 4; ++rg) {
                        int r = rbase + rg;
                        int joint = r % 22;            // tok0 % 22 == 0
                        float val = acc[mi][ni][rg] + pewb[joint * NOUT + pcol];
                        dst[r * str] = f2b(val);
                    }
                }
            }
        }
        __syncthreads();

        // ---- attention: 2 threads per (row, local head); d split 16+16 ----
        if (t < 2 * 2 * MROWS) {          // 352 active
            const int rid = t >> 1;
            const int dh  = (t & 1) << 4;
            const int hl  = (rid >= MROWS) ? 1 : 0;
            const int r   = rid - hl * MROWS;
            const int fr  = r / 22;

            float q[16];
            {
                const unsigned short* qp = &q_s[(hl * MROWS + r) * QSTR + dh];
                union { uint4 v; unsigned int w[4]; } a0, a1;
                a0.v = *(const uint4*)(qp);
                a1.v = *(const uint4*)(qp + 8);
                #pragma unroll
                for (int i = 0; i < 4; ++i) {
                    q[2 * i]     = blo(a0.w[i]) * 0.17677669529663688f;  // 1/sqrt(32)
                    q[2 * i + 1] = bhi(a0.w[i]) * 0.17677669529663688f;
                    q[8 + 2 * i]     = blo(a1.w[i]) * 0.17677669529663688f;
                    q[8 + 2 * i + 1] = bhi(a1.w[i]) * 0.17677669529663688f;
                }
            }

            const unsigned short* kp = &k_s[(hl * MROWS + fr * 22) * 32 + dh];
            float sc[22];
            float mx = -3.0e38f;
            #pragma unroll
            for (int j = 0; j < 22; ++j) {
                union { uint4 v; unsigned int w[4]; } a0, a1;
                a0.v = *(const uint4*)(kp + j * 32);
                a1.v = *(const uint4*)(kp + j * 32 + 8);
                float s = 0.f;
                #pragma unroll
                for (int i = 0; i < 4; ++i) {
                    s += q[2 * i]     * blo(a0.w[i]);
                    s += q[2 * i + 1] * bhi(a0.w[i]);
                    s += q[8 + 2 * i]     * blo(a1.w[i]);
                    s += q[8 + 2 * i + 1] * bhi(a1.w[i]);
                }
                s += __shfl_xor(s, 1);    // combine the two d-halves
                sc[j] = s;
                mx = fmaxf(mx, s);
            }
            float sum = 0.f;
            #pragma unroll
            for (int j = 0; j < 22; ++j) { sc[j] = __expf(sc[j] - mx); sum += sc[j]; }
            float inv = 1.f / sum;

            float o[16];
            #pragma unroll
            for (int d = 0; d < 16; ++d) o[d] = 0.f;
            const unsigned short* vp = &v_s[(hl * MROWS + fr * 22) * 32 + dh];
            #pragma unroll
            for (int j = 0; j < 22; ++j) {
                float p = sc[j] * inv;
                union { uint4 v; unsigned int w[4]; } a0, a1;
                a0.v = *(const uint4*)(vp + j * 32);
                a1.v = *(const uint4*)(vp + j * 32 + 8);
                #pragma unroll
                for (int i = 0; i < 4; ++i) {
                    o[2 * i]     += p * blo(a0.w[i]);
                    o[2 * i + 1] += p * bhi(a0.w[i]);
                    o[8 + 2 * i]     += p * blo(a1.w[i]);
                    o[8 + 2 * i + 1] += p * bhi(a1.w[i]);
                }
            }

            float* op = out + (size_t)(tok0 + r) * DM + ((h0 + hl) << 5) + dh;
            *(float4*)(op)      = make_float4(o[0],  o[1],  o[2],  o[3]);
            *(float4*)(op + 4)  = make_float4(o[4],  o[5],  o[6],  o[7]);
            *(float4*)(op + 8)  = make_float4(o[8],  o[9],  o[10], o[11]);
            *(float4*)(op + 12) = make_float4(o[12], o[13], o[14], o[15]);
        }
        // no barrier here: next iter's MFMA doesn't touch q/k/v; its pre-epilogue
        // barrier protects the buffers. Waves 6-7 (no attn rows) run ahead into MFMA.
    }
}

extern "C" void kernel_launch(void* const* d_in, const int* in_sizes, int n_in,
                              void* d_out, int out_size, void* d_ws, size_t ws_size,
                              hipStream_t stream) {
    const float* x  = (const float*)d_in[0];
    const float* wq = (const float*)d_in[1];
    const float* bq = (const float*)d_in[2];
    const float* wk = (const float*)d_in[3];
    const float* bk = (const float*)d_in[4];
    const float* wv = (const float*)d_in[5];
    const float* bv = (const float*)d_in[6];

    char* ws = (char*)d_ws;
    float*          pewb = (float*)(ws + OFF_PEWB);
    unsigned short* wcan = (unsigned short*)(ws + OFF_WCAN);

    wconv_kernel<<<dim3(32, 3), dim3(256), 0, stream>>>(wq, wk, wv, wcan);
    pewb_kernel<<<dim3(66), dim3(256), 0, stream>>>(wq, wk, wv, bq, bk, bv, pewb);
    fused_kernel<<<dim3(NBLK), dim3(512), 0, stream>>>(x, wcan, pewb, (float*)d_out);
}